// Round 4
// baseline (350.354 us; speedup 1.0000x reference)
//
#include <hip/hip_runtime.h>
#include <math.h>

// GATv2 (in_ch=1, edge_dim=1, H=2, C=64) + fc, collapsed to rank-1/rank-2 algebra.
//
// Round 4: two-pass LDS-binned partition. k_bin: per-edge payload staged in LDS
// by dst-bucket (1024 nodes/bucket), drained coalesced to block-private global
// region (bucket-sorted) + transposed offset table. ZERO global atomics on hot
// path. k_reduce: per-bucket block gathers segments, LDS float atomics, self-
// loop + S. Random-transaction count/edge: ~0 (x[] gathers are L2-resident).
//
// ws layout: rec[S_BLOCKS*2048] int4 | acc[8N] f32 (overflow fallback, memset0)
//            | S[2N] | C[1152] (consts+flag) | offsT[(NB+1)*S_BLOCKS] int

#define LRELU_A1 0.6f   // leakyrelu(v) = 0.6 v + 0.4 |v|  (slope 0.2)
#define LRELU_A2 0.4f
#define NPB      1024   // nodes per bucket (dst>>10)
#define NB_MAX   104
#define TB_BIN   512
#define EPB      2048   // edges per bin block
#define CAP      36     // LDS staging slots per bucket

__global__ void k_prep(const unsigned int* __restrict__ ei,
                       const float* __restrict__ att,
                       const float* __restrict__ W_l,
                       const float* __restrict__ b_l, const float* __restrict__ b_r,
                       const float* __restrict__ bias_out,
                       const float* __restrict__ W_fc, const float* __restrict__ b_fc,
                       float* __restrict__ C) {
  int j = threadIdx.x;
  // int64-vs-int32 edge_index detect: wave-0 lanes 0..31 check high words
  unsigned long long nz = __ballot(j < 32 && ei[2 * j + 1] != 0u);
  if (j == 0) ((int*)C)[1024] = (nz == 0ull) ? 1 : 0;
  if (j >= 128) return;
  float a = att[j];
  C[j] = LRELU_A1 * a;          // A1
  C[128 + j] = LRELU_A2 * a;    // A2
  C[256 + j] = b_l[j] + b_r[j]; // BASE
  const float* wrow = W_fc + j * 256;
  float u0 = 0.f, u1 = 0.f, v0 = 0.f, v1 = 0.f, cb = b_fc[j];
  for (int c = 0; c < 64; c++) {
    u0 = fmaf(W_l[c],      wrow[c],       u0);
    u1 = fmaf(W_l[64 + c], wrow[64 + c],  u1);
    v0 = fmaf(W_l[c],      wrow[128 + c], v0);
    v1 = fmaf(W_l[64 + c], wrow[192 + c], v1);
  }
  for (int t = 0; t < 128; t++) {
    float gb = b_l[t] + bias_out[t];
    cb = fmaf(gb, wrow[t] + wrow[128 + t], cb);
  }
  C[384 + j] = u0;  // U0
  C[512 + j] = u1;  // U1
  C[640 + j] = v0;  // V0
  C[768 + j] = v1;  // V1
  C[896 + j] = cb;  // CB
}

#define CH_STEP(comp, ACC, i)                                                      \
  do {                                                                             \
    float v_ = fmaf(xs4[i], wl.comp, fmaf(xt4[i], wr.comp, fmaf(ae4[i], we.comp, bb.comp))); \
    ACC[i] = fmaf(a2.comp, fabsf(v_), fmaf(a1.comp, v_, ACC[i]));                  \
  } while (0)

__global__ __launch_bounds__(TB_BIN, 4) void k_bin(
    const float* __restrict__ x, const int* __restrict__ ei,
    const float* __restrict__ ea,
    const float* __restrict__ WL, const float* __restrict__ WR,
    const float* __restrict__ WE, const float* __restrict__ C,
    int4* __restrict__ rec, int* __restrict__ offsT, float* __restrict__ acc,
    int NB, int S_BLOCKS, int E) {
  __shared__ int4 stag[NB_MAX * CAP];
  __shared__ int  cnt[NB_MAX];
  __shared__ int  pfx[128];
  const int tid = threadIdx.x;
  for (int i = tid; i < NB_MAX; i += TB_BIN) cnt[i] = 0;
  __syncthreads();

  const int e0 = blockIdx.x * EPB;
  const bool w64 = ((const int*)C)[1024] != 0;
  const float* A1 = C;
  const float* A2 = C + 128;
  const float* BASE = C + 256;

  int de[4];
  float ae4[4], xs4[4], xt4[4];
  bool ok[4];
#pragma unroll
  for (int i = 0; i < 4; i++) {
    int e = e0 + i * TB_BIN + tid;       // coalesced per round
    ok[i] = (e < E);
    int ee = ok[i] ? e : 0;
    int s_ = w64 ? ei[2 * ee] : ei[ee];
    int d_ = w64 ? ei[2 * (E + ee)] : ei[E + ee];
    de[i] = d_;
    ae4[i] = ea[ee];
    xs4[i] = x[s_];
    xt4[i] = x[d_];
  }
  float acc0[4] = {0.f, 0.f, 0.f, 0.f};
  float acc1[4] = {0.f, 0.f, 0.f, 0.f};
#pragma unroll 4
  for (int jb = 0; jb < 64; jb += 4) {
    float4 wl = *(const float4*)(WL + jb);
    float4 wr = *(const float4*)(WR + jb);
    float4 we = *(const float4*)(WE + jb);
    float4 bb = *(const float4*)(BASE + jb);
    float4 a1 = *(const float4*)(A1 + jb);
    float4 a2 = *(const float4*)(A2 + jb);
#pragma unroll
    for (int i = 0; i < 4; i++) {
      CH_STEP(x, acc0, i); CH_STEP(y, acc0, i); CH_STEP(z, acc0, i); CH_STEP(w, acc0, i);
    }
  }
#pragma unroll 4
  for (int jb = 64; jb < 128; jb += 4) {
    float4 wl = *(const float4*)(WL + jb);
    float4 wr = *(const float4*)(WR + jb);
    float4 we = *(const float4*)(WE + jb);
    float4 bb = *(const float4*)(BASE + jb);
    float4 a1 = *(const float4*)(A1 + jb);
    float4 a2 = *(const float4*)(A2 + jb);
#pragma unroll
    for (int i = 0; i < 4; i++) {
      CH_STEP(x, acc1, i); CH_STEP(y, acc1, i); CH_STEP(z, acc1, i); CH_STEP(w, acc1, i);
    }
  }
#pragma unroll
  for (int i = 0; i < 4; i++) {
    if (!ok[i]) continue;
    float eh0 = __expf(acc0[i]);
    float eh1 = __expf(acc1[i]);
    int d_ = de[i];
    int b = d_ >> 10;
    unsigned eab = (__float_as_uint(ae4[i]) & ~1023u) | (unsigned)(d_ & 1023);
    int slot = atomicAdd(&cnt[b], 1);
    if (slot < CAP) {
      stag[b * CAP + slot] = make_int4(__float_as_int(eh0), __float_as_int(eh1),
                                       __float_as_int(xs4[i]), (int)eab);
    } else {  // ultra-rare overflow: direct global accumulation
      float* a = acc + (size_t)d_ * 8;
      atomicAdd(a + 0, eh0);
      atomicAdd(a + 1, eh0 * xs4[i]);
      atomicAdd(a + 2, eh1);
      atomicAdd(a + 3, eh1 * xs4[i]);
      atomicAdd(a + 4, ae4[i]);
      atomicAdd(a + 5, 1.0f);
    }
  }
  __syncthreads();
  // inclusive scan over staged counts (128-wide Hillis-Steele)
  if (tid < 128) pfx[tid] = (tid < NB) ? min(cnt[tid], CAP) : 0;
  __syncthreads();
  for (int st = 1; st < 128; st <<= 1) {
    int v = 0;
    if (tid < 128 && tid >= st) v = pfx[tid - st];
    __syncthreads();
    if (tid < 128) pfx[tid] += v;
    __syncthreads();
  }
  // transposed offset table: offsT[b][s]; row NB = block total
  if (tid < NB + 1) {
    int v = (tid == 0) ? 0 : pfx[tid - 1];
    offsT[(size_t)tid * S_BLOCKS + blockIdx.x] = v;
  }
  const int total = pfx[127];
  int4* myrec = rec + (size_t)blockIdx.x * EPB;
  for (int t = tid; t < total; t += TB_BIN) {
    int lo = 0, hi = NB - 1;
    while (lo < hi) { int mid = (lo + hi) >> 1; if (pfx[mid] > t) hi = mid; else lo = mid + 1; }
    int base = (lo == 0) ? 0 : pfx[lo - 1];
    myrec[t] = stag[lo * CAP + (t - base)];
  }
}

__global__ __launch_bounds__(1024, 2) void k_reduce(
    const float* __restrict__ x,
    const float* __restrict__ WL, const float* __restrict__ WR,
    const float* __restrict__ WE, const float* __restrict__ C,
    const int4* __restrict__ rec, const int* __restrict__ offsT,
    const float* __restrict__ acc, float* __restrict__ S,
    int NB, int S_BLOCKS, int N) {
  __shared__ float lacc[NPB * 7];   // stride 7: bank-conflict-friendly
  __shared__ int sstart[1024];
  __shared__ int spfx[1024];
  const int tid = threadIdx.x;
  const int b = blockIdx.x;
  for (int i = tid; i < NPB * 7; i += 1024) lacc[i] = 0.f;
  int st = 0, len = 0;
  if (tid < S_BLOCKS) {
    st = offsT[(size_t)b * S_BLOCKS + tid];
    int en = offsT[(size_t)(b + 1) * S_BLOCKS + tid];
    len = en - st;
  }
  sstart[tid] = st;
  spfx[tid] = len;
  __syncthreads();
  for (int stp = 1; stp < 1024; stp <<= 1) {
    int v = (tid >= stp) ? spfx[tid - stp] : 0;
    __syncthreads();
    spfx[tid] += v;
    __syncthreads();
  }
  const int T = spfx[1023];
  for (int i = tid; i < T; i += 1024) {
    int lo = 0, hi = S_BLOCKS - 1;
    while (lo < hi) { int mid = (lo + hi) >> 1; if (spfx[mid] > i) hi = mid; else lo = mid + 1; }
    int base = (lo == 0) ? 0 : spfx[lo - 1];
    int4 r = rec[(size_t)lo * EPB + sstart[lo] + (i - base)];
    float e0v = __int_as_float(r.x);
    float e1v = __int_as_float(r.y);
    float xsv = __int_as_float(r.z);
    unsigned eab = (unsigned)r.w;
    int doff = (int)(eab & 1023u);
    float aev = __uint_as_float(eab & ~1023u);
    float* a = lacc + doff * 7;
    atomicAdd(a + 0, e0v);
    atomicAdd(a + 1, e0v * xsv);
    atomicAdd(a + 2, e1v);
    atomicAdd(a + 3, e1v * xsv);
    atomicAdd(a + 4, aev);
    atomicAdd(a + 5, 1.0f);
  }
  __syncthreads();
  const int n = b * NPB + tid;
  if (tid < NPB && n < N) {
    const float* la = lacc + tid * 7;
    const float* g = acc + (size_t)n * 8;
    float den0 = la[0] + g[0], num0 = la[1] + g[1];
    float den1 = la[2] + g[2], num1 = la[3] + g[3];
    float asum = la[4] + g[4], cntv = la[5] + g[5];
    const float* A1 = C;
    const float* A2 = C + 128;
    const float* BASE = C + 256;
    float xn = x[n];
    float am = asum / fmaxf(cntv, 1.0f);
    float acc0 = 0.f, acc1 = 0.f;
#pragma unroll 4
    for (int jb = 0; jb < 64; jb += 4) {
      float4 wl = *(const float4*)(WL + jb);
      float4 wr = *(const float4*)(WR + jb);
      float4 we = *(const float4*)(WE + jb);
      float4 bb = *(const float4*)(BASE + jb);
      float4 a1 = *(const float4*)(A1 + jb);
      float4 a2 = *(const float4*)(A2 + jb);
      float v;
      v = fmaf(xn, wl.x + wr.x, fmaf(am, we.x, bb.x)); acc0 = fmaf(a2.x, fabsf(v), fmaf(a1.x, v, acc0));
      v = fmaf(xn, wl.y + wr.y, fmaf(am, we.y, bb.y)); acc0 = fmaf(a2.y, fabsf(v), fmaf(a1.y, v, acc0));
      v = fmaf(xn, wl.z + wr.z, fmaf(am, we.z, bb.z)); acc0 = fmaf(a2.z, fabsf(v), fmaf(a1.z, v, acc0));
      v = fmaf(xn, wl.w + wr.w, fmaf(am, we.w, bb.w)); acc0 = fmaf(a2.w, fabsf(v), fmaf(a1.w, v, acc0));
    }
#pragma unroll 4
    for (int jb = 64; jb < 128; jb += 4) {
      float4 wl = *(const float4*)(WL + jb);
      float4 wr = *(const float4*)(WR + jb);
      float4 we = *(const float4*)(WE + jb);
      float4 bb = *(const float4*)(BASE + jb);
      float4 a1 = *(const float4*)(A1 + jb);
      float4 a2 = *(const float4*)(A2 + jb);
      float v;
      v = fmaf(xn, wl.x + wr.x, fmaf(am, we.x, bb.x)); acc1 = fmaf(a2.x, fabsf(v), fmaf(a1.x, v, acc1));
      v = fmaf(xn, wl.y + wr.y, fmaf(am, we.y, bb.y)); acc1 = fmaf(a2.y, fabsf(v), fmaf(a1.y, v, acc1));
      v = fmaf(xn, wl.z + wr.z, fmaf(am, we.z, bb.z)); acc1 = fmaf(a2.z, fabsf(v), fmaf(a1.z, v, acc1));
      v = fmaf(xn, wl.w + wr.w, fmaf(am, we.w, bb.w)); acc1 = fmaf(a2.w, fabsf(v), fmaf(a1.w, v, acc1));
    }
    float s0 = __expf(acc0), s1 = __expf(acc1);
    float2 sv;
    sv.x = (num0 + s0 * xn) / (den0 + s0);
    sv.y = (num1 + s1 * xn) / (den1 + s1);
    *(float2*)(S + 2 * n) = sv;
  }
}

__global__ __launch_bounds__(256) void k_out(
    const float* __restrict__ S, const float* __restrict__ C,
    const int* __restrict__ tgtp, float* __restrict__ out, int N) {
  int g = blockIdx.x * blockDim.x + threadIdx.x;
  if (g >= N * 32) return;
  int n = g >> 5;
  int kq = (g & 31) * 4;
  int T = tgtp[0];  // low word valid for int32 and little-endian int64
  float s0t = S[2 * T], s1t = S[2 * T + 1];
  float2 s = *(const float2*)(S + 2 * n);
  float4 u0 = *(const float4*)(C + 384 + kq);
  float4 u1 = *(const float4*)(C + 512 + kq);
  float4 v0 = *(const float4*)(C + 640 + kq);
  float4 v1 = *(const float4*)(C + 768 + kq);
  float4 cb = *(const float4*)(C + 896 + kq);
  float4 o;
  o.x = fmaf(s.x, u0.x, fmaf(s.y, u1.x, fmaf(s0t, v0.x, fmaf(s1t, v1.x, cb.x))));
  o.y = fmaf(s.x, u0.y, fmaf(s.y, u1.y, fmaf(s0t, v0.y, fmaf(s1t, v1.y, cb.y))));
  o.z = fmaf(s.x, u0.z, fmaf(s.y, u1.z, fmaf(s0t, v0.z, fmaf(s1t, v1.z, cb.z))));
  o.w = fmaf(s.x, u0.w, fmaf(s.y, u1.w, fmaf(s0t, v0.w, fmaf(s1t, v1.w, cb.w))));
  *(float4*)(out + n * 128 + kq) = o;
}

extern "C" void kernel_launch(void* const* d_in, const int* in_sizes, int n_in,
                              void* d_out, int out_size, void* d_ws, size_t ws_size,
                              hipStream_t stream) {
  const float* x        = (const float*)d_in[0];
  const int*   ei       = (const int*)d_in[1];
  const float* ea       = (const float*)d_in[2];
  const int*   tgt      = (const int*)d_in[3];
  const float* W_l      = (const float*)d_in[4];
  const float* b_l      = (const float*)d_in[5];
  const float* W_r      = (const float*)d_in[6];
  const float* b_r      = (const float*)d_in[7];
  const float* W_e      = (const float*)d_in[8];
  const float* att      = (const float*)d_in[9];
  const float* bias_out = (const float*)d_in[10];
  const float* W_fc     = (const float*)d_in[11];
  const float* b_fc     = (const float*)d_in[12];

  const int N = in_sizes[0];
  const int E = in_sizes[2];
  const int NB = (N + NPB - 1) / NPB;          // 98
  const int S_BLOCKS = (E + EPB - 1) / EPB;    // 782

  char* p = (char*)d_ws;
  int4*  rec   = (int4*)p;                              p += (size_t)S_BLOCKS * EPB * 16;
  float* acc   = (float*)p;                             p += (size_t)8 * N * 4;
  float* S     = (float*)p;                             p += (size_t)2 * N * 4;
  float* C     = (float*)p;                             p += 1152 * 4;
  int*   offsT = (int*)p;

  hipMemsetAsync(acc, 0, sizeof(float) * (size_t)8 * N, stream);
  k_prep<<<1, 128, 0, stream>>>((const unsigned int*)ei, att, W_l, b_l, b_r,
                                bias_out, W_fc, b_fc, C);
  k_bin<<<S_BLOCKS, TB_BIN, 0, stream>>>(x, ei, ea, W_l, W_r, W_e, C,
                                         rec, offsT, acc, NB, S_BLOCKS, E);
  k_reduce<<<NB, 1024, 0, stream>>>(x, W_l, W_r, W_e, C, rec, offsT, acc, S,
                                    NB, S_BLOCKS, N);
  k_out<<<(N * 32 + 255) / 256, 256, 0, stream>>>(S, C, tgt, (float*)d_out, N);
}

// Round 5
// 239.596 us; speedup vs baseline: 1.4623x; 1.4623x over previous
//
#include <hip/hip_runtime.h>
#include <math.h>

// GATv2 (in_ch=1, edge_dim=1, H=2, C=64) + fc, collapsed to rank-1/rank-2 algebra.
//
// Round 5: two-pass partition, zero fabric-random ops, zero global atomics.
// k_bin: 782 blocks x 2048 edges; payloads in REGISTERS; LDS only for 782
//   bucket counters (128 nodes/bucket) + scan; direct-indexed coalesced-ish
//   drain into block-private global region (L2-local), transposed offset table.
// k_reduce: one block per bucket (782 blocks, 3/CU); gathers its segments,
//   ~12K LDS atomics/block into 128x6 accum; fused self-loop + S finalize.
//
// ws: rec[S_BLOCKS*2048] int4 | offsT[(NB+1)*S_BLOCKS] int | S[2N] f32 | C[1152] f32

#define LRELU_A1 0.6f   // leakyrelu(v) = 0.6 v + 0.4 |v|  (slope 0.2)
#define LRELU_A2 0.4f
#define TB       256
#define EPB      2048   // edges per bin block
#define NPB      128    // nodes per bucket (dst>>7)
#define NB_MAX   1024
#define SB_MAX   1024

__global__ void k_prep(const unsigned int* __restrict__ ei,
                       const float* __restrict__ att,
                       const float* __restrict__ W_l,
                       const float* __restrict__ b_l, const float* __restrict__ b_r,
                       const float* __restrict__ bias_out,
                       const float* __restrict__ W_fc, const float* __restrict__ b_fc,
                       float* __restrict__ C) {
  int j = threadIdx.x;
  unsigned long long nz = __ballot(j < 32 && ei[2 * j + 1] != 0u);
  if (j == 0) ((int*)C)[1024] = (nz == 0ull) ? 1 : 0;   // 1 => int64 indices
  if (j >= 128) return;
  float a = att[j];
  C[j] = LRELU_A1 * a;          // A1
  C[128 + j] = LRELU_A2 * a;    // A2
  C[256 + j] = b_l[j] + b_r[j]; // BASE
  const float* wrow = W_fc + j * 256;
  float u0 = 0.f, u1 = 0.f, v0 = 0.f, v1 = 0.f, cb = b_fc[j];
  for (int c = 0; c < 64; c++) {
    u0 = fmaf(W_l[c],      wrow[c],       u0);
    u1 = fmaf(W_l[64 + c], wrow[64 + c],  u1);
    v0 = fmaf(W_l[c],      wrow[128 + c], v0);
    v1 = fmaf(W_l[64 + c], wrow[192 + c], v1);
  }
  for (int t = 0; t < 128; t++) {
    float gb = b_l[t] + bias_out[t];
    cb = fmaf(gb, wrow[t] + wrow[128 + t], cb);
  }
  C[384 + j] = u0;  // U0
  C[512 + j] = u1;  // U1
  C[640 + j] = v0;  // V0
  C[768 + j] = v1;  // V1
  C[896 + j] = cb;  // CB
}

#define CH_STEP(comp, ACC, i)                                                      \
  do {                                                                             \
    float v_ = fmaf(xs8[i], wl.comp, fmaf(xt8[i], wr.comp, fmaf(ae8[i], we.comp, bb.comp))); \
    ACC[i] = fmaf(a2.comp, fabsf(v_), fmaf(a1.comp, v_, ACC[i]));                  \
  } while (0)

__global__ __launch_bounds__(TB, 4) void k_bin(
    const float* __restrict__ x, const int* __restrict__ ei,
    const float* __restrict__ ea,
    const float* __restrict__ WL, const float* __restrict__ WR,
    const float* __restrict__ WE, const float* __restrict__ C,
    int4* __restrict__ rec, int* __restrict__ offsT,
    int NB, int S_BLOCKS, int E) {
  __shared__ int cnt[NB_MAX];
  __shared__ int pfx[NB_MAX + 1];
  __shared__ int sc[TB];
  const int tid = threadIdx.x;
  for (int i = tid; i < NB_MAX; i += TB) cnt[i] = 0;
  __syncthreads();

  const int e0 = blockIdx.x * EPB;
  const bool w64 = ((const int*)C)[1024] != 0;
  const float* A1 = C;
  const float* A2 = C + 128;
  const float* BASE = C + 256;

  int de8[8];
  float ae8[8], xs8[8], xt8[8];
  bool ok[8];
#pragma unroll
  for (int i = 0; i < 8; i++) {
    int e = e0 + i * TB + tid;   // coalesced per round
    ok[i] = (e < E);
    int ee = ok[i] ? e : 0;
    int s_ = w64 ? ei[2 * ee] : ei[ee];
    int d_ = w64 ? ei[2 * (E + ee)] : ei[E + ee];
    de8[i] = d_;
    ae8[i] = ea[ee];
    xs8[i] = x[s_];
    xt8[i] = x[d_];
  }
  float acc0[8] = {0.f, 0.f, 0.f, 0.f, 0.f, 0.f, 0.f, 0.f};
  float acc1[8] = {0.f, 0.f, 0.f, 0.f, 0.f, 0.f, 0.f, 0.f};
#pragma unroll 2
  for (int jb = 0; jb < 64; jb += 4) {
    float4 wl = *(const float4*)(WL + jb);
    float4 wr = *(const float4*)(WR + jb);
    float4 we = *(const float4*)(WE + jb);
    float4 bb = *(const float4*)(BASE + jb);
    float4 a1 = *(const float4*)(A1 + jb);
    float4 a2 = *(const float4*)(A2 + jb);
#pragma unroll
    for (int i = 0; i < 8; i++) {
      CH_STEP(x, acc0, i); CH_STEP(y, acc0, i); CH_STEP(z, acc0, i); CH_STEP(w, acc0, i);
    }
  }
#pragma unroll 2
  for (int jb = 64; jb < 128; jb += 4) {
    float4 wl = *(const float4*)(WL + jb);
    float4 wr = *(const float4*)(WR + jb);
    float4 we = *(const float4*)(WE + jb);
    float4 bb = *(const float4*)(BASE + jb);
    float4 a1 = *(const float4*)(A1 + jb);
    float4 a2 = *(const float4*)(A2 + jb);
#pragma unroll
    for (int i = 0; i < 8; i++) {
      CH_STEP(x, acc1, i); CH_STEP(y, acc1, i); CH_STEP(z, acc1, i); CH_STEP(w, acc1, i);
    }
  }
  // payload -> registers; claim slots in LDS
  int b8[8], slot8[8], p0[8], p1[8], p2[8], p3[8];
#pragma unroll
  for (int i = 0; i < 8; i++) {
    int d_ = de8[i];
    b8[i] = d_ >> 7;
    p0[i] = __float_as_int(__expf(acc0[i]));
    p1[i] = __float_as_int(__expf(acc1[i]));
    p2[i] = __float_as_int(xs8[i]);
    p3[i] = (int)((__float_as_uint(ae8[i]) & ~127u) | (unsigned)(d_ & 127));
    slot8[i] = ok[i] ? atomicAdd(&cnt[b8[i]], 1) : 0;
  }
  __syncthreads();
  // two-level exclusive scan of cnt[0..NB)
  int l4[4], mysum = 0;
#pragma unroll
  for (int j = 0; j < 4; j++) {
    int idx = tid * 4 + j;
    l4[j] = (idx < NB) ? cnt[idx] : 0;
    mysum += l4[j];
  }
  sc[tid] = mysum;
  __syncthreads();
  for (int st = 1; st < TB; st <<= 1) {
    int v = (tid >= st) ? sc[tid - st] : 0;
    __syncthreads();
    sc[tid] += v;
    __syncthreads();
  }
  int run = sc[tid] - mysum;
#pragma unroll
  for (int j = 0; j < 4; j++) {
    int idx = tid * 4 + j;
    if (idx < NB) { pfx[idx] = run; run += l4[j]; }
  }
  if (tid == 0) pfx[NB] = sc[TB - 1];
  __syncthreads();
  for (int b = tid; b <= NB; b += TB)
    offsT[(size_t)b * S_BLOCKS + blockIdx.x] = pfx[b];
  // direct-indexed drain from registers (random within 32KB block region; L2-local)
  int4* myrec = rec + (size_t)blockIdx.x * EPB;
#pragma unroll
  for (int i = 0; i < 8; i++) {
    if (ok[i]) myrec[pfx[b8[i]] + slot8[i]] = make_int4(p0[i], p1[i], p2[i], p3[i]);
  }
}

__global__ __launch_bounds__(TB, 4) void k_reduce(
    const float* __restrict__ x,
    const float* __restrict__ WL, const float* __restrict__ WR,
    const float* __restrict__ WE, const float* __restrict__ C,
    const int4* __restrict__ rec, const int* __restrict__ offsT,
    float* __restrict__ S, int S_BLOCKS, int N) {
  __shared__ float lacc[NPB * 7];      // stride 7, bank-friendly
  __shared__ int sstart[SB_MAX];
  __shared__ int spfx[SB_MAX];         // inclusive scan of segment lengths
  __shared__ int sc[TB];
  const int tid = threadIdx.x;
  const int b = blockIdx.x;
  for (int i = tid; i < NPB * 7; i += TB) lacc[i] = 0.f;
  int l4[4], st4[4], mysum = 0;
#pragma unroll
  for (int j = 0; j < 4; j++) {
    int s = tid * 4 + j;
    int st = 0, len = 0;
    if (s < S_BLOCKS) {
      st  = offsT[(size_t)b * S_BLOCKS + s];
      len = offsT[(size_t)(b + 1) * S_BLOCKS + s] - st;
    }
    st4[j] = st; l4[j] = len; mysum += len;
  }
  sc[tid] = mysum;
  __syncthreads();
  for (int st = 1; st < TB; st <<= 1) {
    int v = (tid >= st) ? sc[tid - st] : 0;
    __syncthreads();
    sc[tid] += v;
    __syncthreads();
  }
  int run = sc[tid] - mysum;
#pragma unroll
  for (int j = 0; j < 4; j++) {
    int s = tid * 4 + j;
    if (s < S_BLOCKS) { sstart[s] = st4[j]; run += l4[j]; spfx[s] = run; }
  }
  __syncthreads();
  const int T = sc[TB - 1];
  for (int i = tid; i < T; i += TB) {
    int lo = 0, hi = S_BLOCKS - 1;
    while (lo < hi) { int mid = (lo + hi) >> 1; if (spfx[mid] > i) hi = mid; else lo = mid + 1; }
    int base = (lo == 0) ? 0 : spfx[lo - 1];
    int4 r = rec[(size_t)lo * EPB + sstart[lo] + (i - base)];
    float e0v = __int_as_float(r.x);
    float e1v = __int_as_float(r.y);
    float xsv = __int_as_float(r.z);
    unsigned eab = (unsigned)r.w;
    float* a = lacc + (int)(eab & 127u) * 7;
    float aev = __uint_as_float(eab & ~127u);
    atomicAdd(a + 0, e0v);
    atomicAdd(a + 1, e0v * xsv);
    atomicAdd(a + 2, e1v);
    atomicAdd(a + 3, e1v * xsv);
    atomicAdd(a + 4, aev);
    atomicAdd(a + 5, 1.0f);
  }
  __syncthreads();
  const int n = b * NPB + tid;
  if (tid < NPB && n < N) {
    const float* la = lacc + tid * 7;
    float den0 = la[0], num0 = la[1], den1 = la[2], num1 = la[3];
    float asum = la[4], cntv = la[5];
    const float* A1 = C;
    const float* A2 = C + 128;
    const float* BASE = C + 256;
    float xn = x[n];
    float am = asum / fmaxf(cntv, 1.0f);
    float acc0 = 0.f, acc1 = 0.f;
#pragma unroll 4
    for (int jb = 0; jb < 64; jb += 4) {
      float4 wl = *(const float4*)(WL + jb);
      float4 wr = *(const float4*)(WR + jb);
      float4 we = *(const float4*)(WE + jb);
      float4 bb = *(const float4*)(BASE + jb);
      float4 a1 = *(const float4*)(A1 + jb);
      float4 a2 = *(const float4*)(A2 + jb);
      float v;
      v = fmaf(xn, wl.x + wr.x, fmaf(am, we.x, bb.x)); acc0 = fmaf(a2.x, fabsf(v), fmaf(a1.x, v, acc0));
      v = fmaf(xn, wl.y + wr.y, fmaf(am, we.y, bb.y)); acc0 = fmaf(a2.y, fabsf(v), fmaf(a1.y, v, acc0));
      v = fmaf(xn, wl.z + wr.z, fmaf(am, we.z, bb.z)); acc0 = fmaf(a2.z, fabsf(v), fmaf(a1.z, v, acc0));
      v = fmaf(xn, wl.w + wr.w, fmaf(am, we.w, bb.w)); acc0 = fmaf(a2.w, fabsf(v), fmaf(a1.w, v, acc0));
    }
#pragma unroll 4
    for (int jb = 64; jb < 128; jb += 4) {
      float4 wl = *(const float4*)(WL + jb);
      float4 wr = *(const float4*)(WR + jb);
      float4 we = *(const float4*)(WE + jb);
      float4 bb = *(const float4*)(BASE + jb);
      float4 a1 = *(const float4*)(A1 + jb);
      float4 a2 = *(const float4*)(A2 + jb);
      float v;
      v = fmaf(xn, wl.x + wr.x, fmaf(am, we.x, bb.x)); acc1 = fmaf(a2.x, fabsf(v), fmaf(a1.x, v, acc1));
      v = fmaf(xn, wl.y + wr.y, fmaf(am, we.y, bb.y)); acc1 = fmaf(a2.y, fabsf(v), fmaf(a1.y, v, acc1));
      v = fmaf(xn, wl.z + wr.z, fmaf(am, we.z, bb.z)); acc1 = fmaf(a2.z, fabsf(v), fmaf(a1.z, v, acc1));
      v = fmaf(xn, wl.w + wr.w, fmaf(am, we.w, bb.w)); acc1 = fmaf(a2.w, fabsf(v), fmaf(a1.w, v, acc1));
    }
    float s0 = __expf(acc0), s1 = __expf(acc1);
    float2 sv;
    sv.x = (num0 + s0 * xn) / (den0 + s0);
    sv.y = (num1 + s1 * xn) / (den1 + s1);
    *(float2*)(S + 2 * n) = sv;
  }
}

__global__ __launch_bounds__(256) void k_out(
    const float* __restrict__ S, const float* __restrict__ C,
    const int* __restrict__ tgtp, float* __restrict__ out, int N) {
  int g = blockIdx.x * blockDim.x + threadIdx.x;
  if (g >= N * 32) return;
  int n = g >> 5;
  int kq = (g & 31) * 4;
  int T = tgtp[0];  // low word valid for int32 and little-endian int64
  float s0t = S[2 * T], s1t = S[2 * T + 1];
  float2 s = *(const float2*)(S + 2 * n);
  float4 u0 = *(const float4*)(C + 384 + kq);
  float4 u1 = *(const float4*)(C + 512 + kq);
  float4 v0 = *(const float4*)(C + 640 + kq);
  float4 v1 = *(const float4*)(C + 768 + kq);
  float4 cb = *(const float4*)(C + 896 + kq);
  float4 o;
  o.x = fmaf(s.x, u0.x, fmaf(s.y, u1.x, fmaf(s0t, v0.x, fmaf(s1t, v1.x, cb.x))));
  o.y = fmaf(s.x, u0.y, fmaf(s.y, u1.y, fmaf(s0t, v0.y, fmaf(s1t, v1.y, cb.y))));
  o.z = fmaf(s.x, u0.z, fmaf(s.y, u1.z, fmaf(s0t, v0.z, fmaf(s1t, v1.z, cb.z))));
  o.w = fmaf(s.x, u0.w, fmaf(s.y, u1.w, fmaf(s0t, v0.w, fmaf(s1t, v1.w, cb.w))));
  *(float4*)(out + n * 128 + kq) = o;
}

extern "C" void kernel_launch(void* const* d_in, const int* in_sizes, int n_in,
                              void* d_out, int out_size, void* d_ws, size_t ws_size,
                              hipStream_t stream) {
  const float* x        = (const float*)d_in[0];
  const int*   ei       = (const int*)d_in[1];
  const float* ea       = (const float*)d_in[2];
  const int*   tgt      = (const int*)d_in[3];
  const float* W_l      = (const float*)d_in[4];
  const float* b_l      = (const float*)d_in[5];
  const float* W_r      = (const float*)d_in[6];
  const float* b_r      = (const float*)d_in[7];
  const float* W_e      = (const float*)d_in[8];
  const float* att      = (const float*)d_in[9];
  const float* bias_out = (const float*)d_in[10];
  const float* W_fc     = (const float*)d_in[11];
  const float* b_fc     = (const float*)d_in[12];

  const int N = in_sizes[0];
  const int E = in_sizes[2];
  const int NB = (N + NPB - 1) / NPB;          // 782 buckets
  const int S_BLOCKS = (E + EPB - 1) / EPB;    // 782 bin blocks

  char* p = (char*)d_ws;
  int4*  rec   = (int4*)p;                      p += (size_t)S_BLOCKS * EPB * 16;
  int*   offsT = (int*)p;                       p += (size_t)(NB + 1) * S_BLOCKS * 4;
  float* S     = (float*)p;                     p += (size_t)2 * N * 4;
  float* C     = (float*)p;

  k_prep<<<1, 128, 0, stream>>>((const unsigned int*)ei, att, W_l, b_l, b_r,
                                bias_out, W_fc, b_fc, C);
  k_bin<<<S_BLOCKS, TB, 0, stream>>>(x, ei, ea, W_l, W_r, W_e, C,
                                     rec, offsT, NB, S_BLOCKS, E);
  k_reduce<<<NB, TB, 0, stream>>>(x, W_l, W_r, W_e, C, rec, offsT, S,
                                  S_BLOCKS, N);
  k_out<<<(N * 32 + 255) / 256, 256, 0, stream>>>(S, C, tgt, (float*)d_out, N);
}